// Round 2
// baseline (1935.482 us; speedup 1.0000x reference)
//
#include <hip/hip_runtime.h>

typedef __attribute__((ext_vector_type(8))) short bf16x8;
typedef __attribute__((ext_vector_type(4))) float f32x4;

__device__ __forceinline__ unsigned short f2bf(float f) {
  unsigned u = __builtin_bit_cast(unsigned, f);
  u += 0x7fffu + ((u >> 16) & 1u);  // RNE
  return (unsigned short)(u >> 16);
}
__device__ __forceinline__ float bf2f(unsigned short s) {
  unsigned u = ((unsigned)s) << 16;
  return __builtin_bit_cast(float, u);
}
__device__ __forceinline__ bf16x8 zero8() {
  bf16x8 r;
#pragma unroll
  for (int i = 0; i < 8; ++i) r[i] = 0;
  return r;
}
__device__ __forceinline__ bf16x8 cvt8(f32x4 a, f32x4 b) {
  bf16x8 f;
#pragma unroll
  for (int j = 0; j < 4; ++j) {
    f[j] = (short)f2bf(a[j]);
    f[j + 4] = (short)f2bf(b[j]);
  }
  return f;
}
// B-frag from row-major [K x 192] f32 matrix: B[k0+j][col], j=0..7 (L2-hot)
__device__ __forceinline__ bf16x8 ldBf(const float* __restrict__ M, int k0, int col) {
  bf16x8 f;
#pragma unroll
  for (int j = 0; j < 8; ++j) f[j] = (short)f2bf(M[(k0 + j) * 192 + col]);
  return f;
}
// same-wave LDS RAW: DS pipe is in-order per wave; only lgkm drain needed.
// (NOT __threadfence_block: that can emit vmcnt(0) and drain our ch prefetch)
#define LGKM0() asm volatile("s_waitcnt lgkmcnt(0)" ::: "memory")

__global__ __launch_bounds__(256, 4) void rann_fused(
    const float* __restrict__ nf, const float* __restrict__ ch,
    const float* __restrict__ Ac, const int* __restrict__ ccnt,
    const float* __restrict__ W, const float* __restrict__ a_src,
    const float* __restrict__ a_dst, const float* __restrict__ Wx,
    const float* __restrict__ Whg, const float* __restrict__ bias,
    float* __restrict__ out, int N, int* counter, int nbatch) {
  __shared__ __align__(16) float srcdst[4][32];             // per-wave src[16],dst[16]
  __shared__ __align__(16) unsigned short wh_t[4][64][16];  // per-wave Wh^T bf16 [h][c]
  __shared__ __align__(16) unsigned short pooledb[4][16][64];

  const int tid = threadIdx.x;
  const int lane = tid & 63;
  const int w = tid >> 6;
  const int q = lane >> 4;
  const int m16 = lane & 15;
  const int qe = q & 1;

  // ---- persistent W B-frags: B[k=32t+8q+j][n=16u+m16] ----
  bf16x8 wfrag[2][4];
#pragma unroll
  for (int t = 0; t < 2; ++t)
#pragma unroll
    for (int u = 0; u < 4; ++u) {
      bf16x8 f;
#pragma unroll
      for (int j = 0; j < 8; ++j)
        f[j] = (short)f2bf(W[(32 * t + 8 * q + j) * 64 + 16 * u + m16]);
      wfrag[t][u] = f;
    }
  // ---- src/dst fused into MFMA: B cols {0:W@a_src, 1:W@a_dst} ----
  float was = 0.f, wad = 0.f;
  for (int h = 0; h < 64; ++h) {
    const float wv = W[lane * 64 + h];
    was += wv * a_src[h];
    wad += wv * a_dst[h];
  }
  bf16x8 bsd[2];
#pragma unroll
  for (int t = 0; t < 2; ++t) {
    bf16x8 f;
#pragma unroll
    for (int j = 0; j < 8; ++j) {
      const int k = 32 * t + 8 * q + j;
      const float vs = __shfl(was, k);
      const float vd = __shfl(wad, k);
      f[j] = (m16 == 0) ? (short)f2bf(vs) : ((m16 == 1) ? (short)f2bf(vd) : (short)0);
    }
    bsd[t] = f;
  }

  int next_static = blockIdx.x * 4 + w;
  for (;;) {
    int bidx;
    if (counter) {
      if (lane == 0) bidx = atomicAdd(counter, 1);
      bidx = __shfl(bidx, 0);
    } else {
      bidx = next_static;
      next_static += gridDim.x * 4;
    }
    if (bidx >= nbatch) break;
    const int nb = bidx << 4;

    // prefetch ch for node 0
    f32x4 chv[4];
    {
      const float* p = ch + (size_t)nb * 1024 + m16 * 64 + 8 * q;
      chv[0] = *(const f32x4*)p;
      chv[1] = *(const f32x4*)(p + 4);
      chv[2] = *(const f32x4*)(p + 32);
      chv[3] = *(const f32x4*)(p + 36);
    }
    for (int s = 0; s < 16; ++s) {
      // ---- prefetch ch for node s+1 ----
      f32x4 chn[4];
      if (s < 15) {
        const float* p = ch + (size_t)(nb + s + 1) * 1024 + m16 * 64 + 8 * q;
        chn[0] = *(const f32x4*)p;
        chn[1] = *(const f32x4*)(p + 4);
        chn[2] = *(const f32x4*)(p + 32);
        chn[3] = *(const f32x4*)(p + 36);
      }
      // ---- issue Ac/ccnt for current node (consumed ~300cyc later) ----
      const float* ap = Ac + (size_t)(nb + s) * 256 + m16 * 16 + 8 * qe;
      const f32x4 ac0 = *(const f32x4*)ap;
      const f32x4 ac1 = *(const f32x4*)(ap + 4);
      const int cc = ccnt[nb + s];

      // ---- Wh = ch @ W  +  fused src/dst columns ----
      const bf16x8 afA0 = cvt8(chv[0], chv[1]);
      const bf16x8 afA1 = cvt8(chv[2], chv[3]);
      f32x4 acc[4];
#pragma unroll
      for (int u = 0; u < 4; ++u) acc[u] = (f32x4){0.f, 0.f, 0.f, 0.f};
#pragma unroll
      for (int u = 0; u < 4; ++u) {
        acc[u] = __builtin_amdgcn_mfma_f32_16x16x32_bf16(afA0, wfrag[0][u], acc[u], 0, 0, 0);
        acc[u] = __builtin_amdgcn_mfma_f32_16x16x32_bf16(afA1, wfrag[1][u], acc[u], 0, 0, 0);
      }
      f32x4 sd = (f32x4){0.f, 0.f, 0.f, 0.f};
      sd = __builtin_amdgcn_mfma_f32_16x16x32_bf16(afA0, bsd[0], sd, 0, 0, 0);
      sd = __builtin_amdgcn_mfma_f32_16x16x32_bf16(afA1, bsd[1], sd, 0, 0, 0);
      if (m16 < 2) *(f32x4*)&srcdst[w][16 * m16 + 4 * q] = sd;  // src[c] / dst[c]

      // ---- Wh -> bf16 LDS transpose (B-operand for MFMA2) ----
#pragma unroll
      for (int u = 0; u < 4; ++u) {
        uint2 v;
        v.x = (unsigned)f2bf(acc[u][0]) | ((unsigned)f2bf(acc[u][1]) << 16);
        v.y = (unsigned)f2bf(acc[u][2]) | ((unsigned)f2bf(acc[u][3]) << 16);
        *(uint2*)&wh_t[w][16 * u + m16][4 * q] = v;
      }
      LGKM0();

      // ---- e + masked softmax in A-operand layout (row i=m16, col j=8qe+jj) ----
      const float srcv = srcdst[w][m16];
      const f32x4 d0 = *(const f32x4*)&srcdst[w][16 + 8 * qe];
      const f32x4 d1 = *(const f32x4*)&srcdst[w][16 + 8 * qe + 4];
      float p8[8];
      float rmax = -3.0e38f;
#pragma unroll
      for (int jj = 0; jj < 8; ++jj) {
        const float dstv = (jj < 4) ? d0[jj] : d1[jj - 4];
        const float av = (jj < 4) ? ac0[jj] : ac1[jj - 4];
        const float x = srcv + dstv;
        const float e = fmaxf(x, 0.2f * x);
        const bool msk = (av > 0.5f) && (m16 < cc) && ((8 * qe + jj) < cc);
        p8[jj] = msk ? e : -1.0e9f;
        rmax = fmaxf(rmax, p8[jj]);
      }
      rmax = fmaxf(rmax, __shfl_xor(rmax, 16));
      float psum = 0.f;
#pragma unroll
      for (int jj = 0; jj < 8; ++jj) {
        p8[jj] = __expf(p8[jj] - rmax);
        psum += p8[jj];
      }
      psum += __shfl_xor(psum, 16);
      const float inv = 1.0f / psum;
      bf16x8 afrag2 = zero8();
      if (q < 2) {
#pragma unroll
        for (int jj = 0; jj < 8; ++jj) afrag2[jj] = (short)f2bf(p8[jj] * inv);
      }
      // ---- h_msg = attn @ Wh (K=16 zero-padded to 32) ----
      f32x4 acc2[4];
#pragma unroll
      for (int u = 0; u < 4; ++u) {
        bf16x8 bf2 = zero8();
        if (q < 2) bf2 = *(const bf16x8*)&wh_t[w][16 * u + m16][8 * q];
        const f32x4 z4 = (f32x4){0.f, 0.f, 0.f, 0.f};
        acc2[u] = __builtin_amdgcn_mfma_f32_16x16x32_bf16(afrag2, bf2, z4, 0, 0, 0);
      }
      // ---- elu + masked maxpool over children ----
#pragma unroll
      for (int u = 0; u < 4; ++u) {
        float pm = -1.0e9f;
#pragma unroll
        for (int r = 0; r < 4; ++r) {
          const float v = acc2[u][r];
          const float ev = v > 0.f ? v : __expf(v) - 1.0f;
          pm = fmaxf(pm, (4 * q + r) < cc ? ev : -1.0e9f);
        }
        pm = fmaxf(pm, __shfl_xor(pm, 16));
        pm = fmaxf(pm, __shfl_xor(pm, 32));
        if (q == 0) pooledb[w][s][16 * u + m16] = f2bf(pm);
      }
      if (s < 15) {
        chv[0] = chn[0]; chv[1] = chn[1]; chv[2] = chn[2]; chv[3] = chn[3];
      }
    }  // s
    LGKM0();

    // ================= GRU, 16 nodes as MFMA M-dim; weights from L2 ==========
    bf16x8 afP[2];
#pragma unroll
    for (int t = 0; t < 2; ++t)
      afP[t] = *(const bf16x8*)&pooledb[w][m16][32 * t + 8 * q];
    bf16x8 afX0, afX1;
    {
      const float* p = nf + (size_t)(nb + m16) * 40 + 8 * q;
      afX0 = cvt8(*(const f32x4*)p, *(const f32x4*)(p + 4));
      afX1 = zero8();
      if (q == 0) {
        const float* p1 = nf + (size_t)(nb + m16) * 40 + 32;
        afX1 = cvt8(*(const f32x4*)p1, *(const f32x4*)(p1 + 4));
      }
    }
    f32x4 accS[8], accNh[4], accNx[4];
#pragma unroll
    for (int u = 0; u < 8; ++u) accS[u] = (f32x4){0.f, 0.f, 0.f, 0.f};
#pragma unroll
    for (int u = 0; u < 4; ++u) {
      accNh[u] = (f32x4){0.f, 0.f, 0.f, 0.f};
      accNx[u] = (f32x4){0.f, 0.f, 0.f, 0.f};
    }
#pragma unroll
    for (int u = 0; u < 8; ++u) {
      const int col = 16 * u + m16;
      accS[u] = __builtin_amdgcn_mfma_f32_16x16x32_bf16(afP[0], ldBf(Whg, 8 * q, col), accS[u], 0, 0, 0);
      accS[u] = __builtin_amdgcn_mfma_f32_16x16x32_bf16(afP[1], ldBf(Whg, 32 + 8 * q, col), accS[u], 0, 0, 0);
      accS[u] = __builtin_amdgcn_mfma_f32_16x16x32_bf16(afX0, ldBf(Wx, 8 * q, col), accS[u], 0, 0, 0);
      const bf16x8 bx1 = (q == 0) ? ldBf(Wx, 32, col) : zero8();
      accS[u] = __builtin_amdgcn_mfma_f32_16x16x32_bf16(afX1, bx1, accS[u], 0, 0, 0);
    }
#pragma unroll
    for (int u = 0; u < 4; ++u) {
      const int col = 128 + 16 * u + m16;
      accNh[u] = __builtin_amdgcn_mfma_f32_16x16x32_bf16(afP[0], ldBf(Whg, 8 * q, col), accNh[u], 0, 0, 0);
      accNh[u] = __builtin_amdgcn_mfma_f32_16x16x32_bf16(afP[1], ldBf(Whg, 32 + 8 * q, col), accNh[u], 0, 0, 0);
      accNx[u] = __builtin_amdgcn_mfma_f32_16x16x32_bf16(afX0, ldBf(Wx, 8 * q, col), accNx[u], 0, 0, 0);
      const bf16x8 bx1 = (q == 0) ? ldBf(Wx, 32, col) : zero8();
      accNx[u] = __builtin_amdgcn_mfma_f32_16x16x32_bf16(afX1, bx1, accNx[u], 0, 0, 0);
    }
    // epilogue: lane holds node 4q+r, col 16u+m16
#pragma unroll
    for (int u = 0; u < 4; ++u) {
      const int col = 16 * u + m16;
      const float bz = bias[col];
      const float br = bias[64 + col];
      const float bn = bias[128 + col];
#pragma unroll
      for (int r = 0; r < 4; ++r) {
        const int nl = 4 * q + r;
        const float z = 1.0f / (1.0f + __expf(-(accS[u][r] + bz)));
        const float rg = 1.0f / (1.0f + __expf(-(accS[u + 4][r] + br)));
        float xv = accNx[u][r] + bn + rg * accNh[u][r];
        xv = fminf(fmaxf(xv, -15.f), 15.f);
        const float t2 = __expf(2.f * xv);
        const float nn = (t2 - 1.f) / (t2 + 1.f);
        const float pv = bf2f(pooledb[w][nl][col]);
        out[(size_t)(nb + nl) * 64 + col] = (1.0f - z) * nn + z * pv;
      }
    }
  }  // batch loop
}

extern "C" void kernel_launch(void* const* d_in, const int* in_sizes, int n_in,
                              void* d_out, int out_size, void* d_ws, size_t ws_size,
                              hipStream_t stream) {
  const float* nf = (const float*)d_in[0];
  const float* ch = (const float*)d_in[1];
  const float* Ac = (const float*)d_in[2];
  const int* ccnt = (const int*)d_in[3];
  const float* W = (const float*)d_in[4];
  const float* a_src = (const float*)d_in[5];
  const float* a_dst = (const float*)d_in[6];
  const float* Wx = (const float*)d_in[7];
  const float* Whg = (const float*)d_in[8];
  const float* bias = (const float*)d_in[9];
  float* out = (float*)d_out;
  const int N = in_sizes[3];
  const int nbatch = N >> 4;
  int* counter = nullptr;
  if (ws_size >= sizeof(int)) {
    counter = (int*)d_ws;
    hipMemsetAsync(d_ws, 0, sizeof(int), stream);  // graph-capturable
  }
  // 4 blocks/CU x 256 CUs = exactly-resident grid; dynamic batch pull
  hipLaunchKernelGGL(rann_fused, dim3(1024), dim3(256), 0, stream,
                     nf, ch, Ac, ccnt, W, a_src, a_dst, Wx, Whg, bias, out, N,
                     counter, nbatch);
}